// Round 1
// baseline (12525.709 us; speedup 1.0000x reference)
//
#include <hip/hip_runtime.h>
#include <hip/hip_bf16.h>
#include <math.h>

// Problem constants
#define BB      64
#define PP      196      // 14*14
#define ENCD    512
#define ADIM    512
#define DDIM    512
#define EDIM    512
#define VDIM    32000
#define MAXLEN  51
#define TSTEPS  50       // MAXLEN - 1
#define KCAT    1536     // E + ENC + D
#define GDIM    2048     // 4*D

// ---------------------------------------------------------------------------
// Workspace layout (float offsets). Total ~27.56M floats = ~110 MB.
#define WS_WFCT      0ull                               // 512 x 32000
#define WS_EA        (WS_WFCT + 512ull*VDIM)            // 64 x 196 x 512
#define WS_WCATT     (WS_EA + (unsigned long long)BB*PP*ADIM)   // 1536 x 2048
#define WS_WENCT     (WS_WCATT + 1536ull*GDIM)          // 512 x 512
#define WS_WDECT     (WS_WENCT + 512ull*512)
#define WS_WFBT      (WS_WDECT + 512ull*512)
#define WS_WIHT      (WS_WFBT + 512ull*512)             // W_init_h^T
#define WS_WICT      (WS_WIHT + 512ull*512)             // W_init_c^T
#define WS_MEAN      (WS_WICT + 512ull*512)             // 64 x 512
#define WS_H         (WS_MEAN + (unsigned long long)BB*ENCD)
#define WS_C         (WS_H + (unsigned long long)BB*DDIM)
#define WS_CTX       (WS_C + (unsigned long long)BB*DDIM)
#define WS_GATE      (WS_CTX + (unsigned long long)BB*ENCD)
#define WS_G         (WS_GATE + (unsigned long long)BB*ENCD)   // 64 x 2048
#define WS_ORDER     (WS_G + (unsigned long long)BB*GDIM)      // int 64
#define WS_DECLEN    (WS_ORDER + 64ull)                        // int 64

// ---------------------------------------------------------------------------
// Sort (stable descending by cap_len), writes caps/dec_len/order outputs.
__global__ __launch_bounds__(64) void k_sort(
    const int* __restrict__ cap_len, const int* __restrict__ caps,
    float* __restrict__ out_caps, float* __restrict__ out_declen,
    float* __restrict__ out_order, int* __restrict__ order_i,
    int* __restrict__ declen_i) {
  __shared__ int lens[BB];
  __shared__ int ord[BB];
  int i = threadIdx.x;
  lens[i] = cap_len[i];
  __syncthreads();
  int li = lens[i];
  int rank = 0;
  for (int j = 0; j < BB; ++j) {
    int lj = lens[j];
    if (lj > li || (lj == li && j < i)) rank++;
  }
  ord[rank] = i;
  __syncthreads();
  int ob = ord[i];
  order_i[i] = ob;
  int dl = lens[ob] - 1;
  declen_i[i] = dl;
  out_declen[i] = (float)dl;
  out_order[i] = (float)ob;
  for (int j = 0; j < MAXLEN; ++j)
    out_caps[i * MAXLEN + j] = (float)caps[ob * MAXLEN + j];
}

// ---------------------------------------------------------------------------
// Tiled transpose: dst[c*dstLD + r] = src[r*C + c]. R,C multiples of 32.
__global__ __launch_bounds__(256) void k_transpose(
    const float* __restrict__ src, int R, int C,
    float* __restrict__ dst, int dstLD) {
  __shared__ float tile[32][33];
  int tx = threadIdx.x, ty = threadIdx.y;   // 32 x 8
  int c0 = blockIdx.x * 32, r0 = blockIdx.y * 32;
  for (int i = ty; i < 32; i += 8)
    tile[i][tx] = src[(size_t)(r0 + i) * C + (c0 + tx)];
  __syncthreads();
  for (int i = ty; i < 32; i += 8)
    dst[(size_t)(c0 + i) * dstLD + (r0 + tx)] = tile[tx][i];
}

// ---------------------------------------------------------------------------
__global__ __launch_bounds__(256) void k_mean(
    const float* __restrict__ enc, const int* __restrict__ order_i,
    float* __restrict__ mean_enc) {
  int b = blockIdx.x;
  int ob = order_i[b];
  const float* src = enc + (size_t)ob * PP * ENCD;
  for (int e = threadIdx.x; e < ENCD; e += 256) {
    float acc = 0.f;
    for (int p = 0; p < PP; ++p) acc += src[p * ENCD + e];
    mean_enc[b * ENCD + e] = acc * (1.f / PP);
  }
}

// ---------------------------------------------------------------------------
__global__ __launch_bounds__(256) void k_init_hc(
    const float* __restrict__ mean_enc, const float* __restrict__ WhT,
    const float* __restrict__ bh, const float* __restrict__ WcT,
    const float* __restrict__ bc, float* __restrict__ h, float* __restrict__ c) {
  __shared__ float m[ENCD];
  int b = blockIdx.x;
  for (int k = threadIdx.x; k < ENCD; k += 256) m[k] = mean_enc[b * ENCD + k];
  __syncthreads();
  for (int d = threadIdx.x; d < DDIM; d += 256) {
    float ah = bh[d], ac = bc[d];
    for (int k = 0; k < ENCD; ++k) {
      float mv = m[k];
      ah += mv * WhT[k * DDIM + d];
      ac += mv * WcT[k * DDIM + d];
    }
    h[b * DDIM + d] = ah;
    c[b * DDIM + d] = ac;
  }
}

// ---------------------------------------------------------------------------
// ea = enc_sorted @ W_enc^T + b_enc.  C is (12544, 512). 64x64 tiles.
__global__ __launch_bounds__(256) void k_ea_gemm(
    const float* __restrict__ enc, const int* __restrict__ order_i,
    const float* __restrict__ WT, const float* __restrict__ bias,
    float* __restrict__ ea) {
  __shared__ float As[16][65];
  __shared__ float Bs[16][65];
  __shared__ const float* rowp[64];
  int row0 = blockIdx.x * 64, n0 = blockIdx.y * 64;
  int tid = threadIdx.x;
  if (tid < 64) {
    int r = row0 + tid;
    rowp[tid] = enc + ((size_t)order_i[r / PP] * PP + (r % PP)) * ENCD;
  }
  __syncthreads();
  float acc[4][4] = {};
  int tx = tid & 15, ty = tid >> 4;
  int lm = tid >> 2, lk = (tid & 3) * 4;
  int lk2 = tid >> 4, ln = (tid & 15) * 4;
  for (int k0 = 0; k0 < 512; k0 += 16) {
    float4 av = *(const float4*)(rowp[lm] + k0 + lk);
    As[lk + 0][lm] = av.x; As[lk + 1][lm] = av.y;
    As[lk + 2][lm] = av.z; As[lk + 3][lm] = av.w;
    float4 bv = *(const float4*)(WT + (size_t)(k0 + lk2) * 512 + n0 + ln);
    Bs[lk2][ln + 0] = bv.x; Bs[lk2][ln + 1] = bv.y;
    Bs[lk2][ln + 2] = bv.z; Bs[lk2][ln + 3] = bv.w;
    __syncthreads();
    for (int kk = 0; kk < 16; ++kk) {
      float a[4], bb[4];
      for (int i = 0; i < 4; ++i) a[i] = As[kk][ty * 4 + i];
      for (int j = 0; j < 4; ++j) bb[j] = Bs[kk][tx * 4 + j];
      for (int i = 0; i < 4; ++i)
        for (int j = 0; j < 4; ++j) acc[i][j] += a[i] * bb[j];
    }
    __syncthreads();
  }
  for (int i = 0; i < 4; ++i) {
    int r = row0 + ty * 4 + i;
    for (int j = 0; j < 4; ++j) {
      int n = n0 + tx * 4 + j;
      ea[(size_t)r * 512 + n] = acc[i][j] + bias[n];
    }
  }
}

// ---------------------------------------------------------------------------
// Attention per step. Blocks 0..63: da+scores+softmax+ctx for b=bid.
// Blocks 64..127: f_beta gate for b=bid-64.
__global__ __launch_bounds__(256) void k_att(
    const float* __restrict__ h, const float* __restrict__ WdecT,
    const float* __restrict__ b_dec, const float* __restrict__ ea,
    const float* __restrict__ w_full, const float* __restrict__ b_full,
    const float* __restrict__ enc, const int* __restrict__ order_i,
    const int* __restrict__ declen_i, const float* __restrict__ WfbT,
    const float* __restrict__ b_fb, float* __restrict__ ctx,
    float* __restrict__ gate, float* __restrict__ out_alphas, int t) {
  __shared__ float hs[DDIM];
  int bid = blockIdx.x;
  int tid = threadIdx.x;
  int b = bid & 63;
  for (int k = tid; k < DDIM; k += 256) hs[k] = h[b * DDIM + k];
  __syncthreads();
  if (bid >= 64) {  // gate path
    for (int d = tid; d < ENCD; d += 256) {
      float acc = b_fb[d];
      for (int k = 0; k < DDIM; ++k) acc += hs[k] * WfbT[k * ENCD + d];
      gate[b * ENCD + d] = 1.f / (1.f + expf(-acc));
    }
    return;
  }
  __shared__ float das[ADIM];
  __shared__ float sc[PP];
  for (int a = tid; a < ADIM; a += 256) {
    float acc = b_dec[a];
    for (int k = 0; k < DDIM; ++k) acc += hs[k] * WdecT[k * ADIM + a];
    das[a] = acc;
  }
  __syncthreads();
  int wave = tid >> 6, lane = tid & 63;
  for (int p = wave; p < PP; p += 4) {
    const float* ep = ea + ((size_t)b * PP + p) * ADIM;
    float s = 0.f;
    for (int a = lane; a < ADIM; a += 64)
      s += fmaxf(ep[a] + das[a], 0.f) * w_full[a];
    for (int off = 32; off; off >>= 1) s += __shfl_down(s, off);
    if (lane == 0) sc[p] = s + b_full[0];
  }
  __syncthreads();
  if (wave == 0) {  // softmax over 196 by wave 0
    float m = -1e30f;
    for (int p = lane; p < PP; p += 64) m = fmaxf(m, sc[p]);
    for (int off = 32; off; off >>= 1) m = fmaxf(m, __shfl_xor(m, off));
    float ssum = 0.f;
    for (int p = lane; p < PP; p += 64) {
      float e = expf(sc[p] - m);
      sc[p] = e;
      ssum += e;
    }
    for (int off = 32; off; off >>= 1) ssum += __shfl_xor(ssum, off);
    float inv = 1.f / ssum;
    for (int p = lane; p < PP; p += 64) sc[p] *= inv;
  }
  __syncthreads();
  int active = t < declen_i[b];
  for (int p = tid; p < PP; p += 256)
    out_alphas[((size_t)b * TSTEPS + t) * PP + p] = active ? sc[p] : 0.f;
  int ob = order_i[b];
  const float* eb = enc + (size_t)ob * PP * ENCD;
  for (int e = tid; e < ENCD; e += 256) {
    float acc = 0.f;
    for (int p = 0; p < PP; ++p) acc += sc[p] * eb[p * ENCD + e];
    ctx[b * ENCD + e] = acc;
  }
}

// ---------------------------------------------------------------------------
// Gates GEMM: g[64,2048] = [emb | ctx*gate | h] @ WcatT(1536x2048). Raw acc.
__global__ __launch_bounds__(256) void k_gates(
    const float* __restrict__ emb_table, const int* __restrict__ caps,
    const int* __restrict__ order_i, const float* __restrict__ ctx,
    const float* __restrict__ gate, const float* __restrict__ h,
    const float* __restrict__ WcatT, float* __restrict__ g, int t) {
  __shared__ float As[16][65];
  __shared__ float Bs[16][65];
  __shared__ int tok[64];
  int n0 = blockIdx.x * 64;
  int tid = threadIdx.x;
  if (tid < 64) tok[tid] = caps[order_i[tid] * MAXLEN + t];
  __syncthreads();
  float acc[4][4] = {};
  int tx = tid & 15, ty = tid >> 4;
  int lm = tid >> 2, lk = (tid & 3) * 4;
  int lk2 = tid >> 4, ln = (tid & 15) * 4;
  for (int k0 = 0; k0 < KCAT; k0 += 16) {
    int k = k0 + lk;
    float4 av;
    if (k < 512) {
      av = *(const float4*)(emb_table + (size_t)tok[lm] * EDIM + k);
    } else if (k < 1024) {
      float4 cv = *(const float4*)(ctx + lm * ENCD + (k - 512));
      float4 gv = *(const float4*)(gate + lm * ENCD + (k - 512));
      av = make_float4(cv.x * gv.x, cv.y * gv.y, cv.z * gv.z, cv.w * gv.w);
    } else {
      av = *(const float4*)(h + lm * DDIM + (k - 1024));
    }
    As[lk + 0][lm] = av.x; As[lk + 1][lm] = av.y;
    As[lk + 2][lm] = av.z; As[lk + 3][lm] = av.w;
    float4 bv = *(const float4*)(WcatT + (size_t)(k0 + lk2) * GDIM + n0 + ln);
    Bs[lk2][ln + 0] = bv.x; Bs[lk2][ln + 1] = bv.y;
    Bs[lk2][ln + 2] = bv.z; Bs[lk2][ln + 3] = bv.w;
    __syncthreads();
    for (int kk = 0; kk < 16; ++kk) {
      float a[4], bb[4];
      for (int i = 0; i < 4; ++i) a[i] = As[kk][ty * 4 + i];
      for (int j = 0; j < 4; ++j) bb[j] = Bs[kk][tx * 4 + j];
      for (int i = 0; i < 4; ++i)
        for (int j = 0; j < 4; ++j) acc[i][j] += a[i] * bb[j];
    }
    __syncthreads();
  }
  for (int i = 0; i < 4; ++i) {
    int bb_ = ty * 4 + i;
    for (int j = 0; j < 4; ++j)
      g[(size_t)bb_ * GDIM + n0 + tx * 4 + j] = acc[i][j];
  }
}

// ---------------------------------------------------------------------------
__global__ __launch_bounds__(512) void k_lstm_pw(
    const float* __restrict__ g, const float* __restrict__ b_ih,
    const float* __restrict__ b_hh, float* __restrict__ h,
    float* __restrict__ c) {
  int b = blockIdx.x, d = threadIdx.x;
  float gi = g[b * GDIM + d] + b_ih[d] + b_hh[d];
  float gf = g[b * GDIM + 512 + d] + b_ih[512 + d] + b_hh[512 + d];
  float gg = g[b * GDIM + 1024 + d] + b_ih[1024 + d] + b_hh[1024 + d];
  float go = g[b * GDIM + 1536 + d] + b_ih[1536 + d] + b_hh[1536 + d];
  float si = 1.f / (1.f + expf(-gi));
  float sf = 1.f / (1.f + expf(-gf));
  float so = 1.f / (1.f + expf(-go));
  float cn = sf * c[b * DDIM + d] + si * tanhf(gg);
  float hn = so * tanhf(cn);
  c[b * DDIM + d] = cn;
  h[b * DDIM + d] = hn;
}

// ---------------------------------------------------------------------------
// fc GEMM: preds[b, t, :] = h @ WfcT + b_fc, masked by (t < dec_len[b]).
__global__ __launch_bounds__(256) void k_fc(
    const float* __restrict__ h, const float* __restrict__ WfcT,
    const float* __restrict__ b_fc, const int* __restrict__ declen_i,
    float* __restrict__ out_pred, int t) {
  __shared__ float As[16][65];
  __shared__ float Bs[16][65];
  __shared__ int dls[64];
  int n0 = blockIdx.x * 64;
  int tid = threadIdx.x;
  if (tid < 64) dls[tid] = declen_i[tid];
  __syncthreads();
  float acc[4][4] = {};
  int tx = tid & 15, ty = tid >> 4;
  int lm = tid >> 2, lk = (tid & 3) * 4;
  int lk2 = tid >> 4, ln = (tid & 15) * 4;
  for (int k0 = 0; k0 < 512; k0 += 16) {
    float4 av = *(const float4*)(h + lm * DDIM + k0 + lk);
    As[lk + 0][lm] = av.x; As[lk + 1][lm] = av.y;
    As[lk + 2][lm] = av.z; As[lk + 3][lm] = av.w;
    float4 bv = *(const float4*)(WfcT + (size_t)(k0 + lk2) * VDIM + n0 + ln);
    Bs[lk2][ln + 0] = bv.x; Bs[lk2][ln + 1] = bv.y;
    Bs[lk2][ln + 2] = bv.z; Bs[lk2][ln + 3] = bv.w;
    __syncthreads();
    for (int kk = 0; kk < 16; ++kk) {
      float a[4], bb[4];
      for (int i = 0; i < 4; ++i) a[i] = As[kk][ty * 4 + i];
      for (int j = 0; j < 4; ++j) bb[j] = Bs[kk][tx * 4 + j];
      for (int i = 0; i < 4; ++i)
        for (int j = 0; j < 4; ++j) acc[i][j] += a[i] * bb[j];
    }
    __syncthreads();
  }
  for (int i = 0; i < 4; ++i) {
    int b = ty * 4 + i;
    int active = t < dls[b];
    float* dst = out_pred + ((size_t)b * TSTEPS + t) * VDIM + n0;
    for (int j = 0; j < 4; ++j) {
      int n = n0 + tx * 4 + j;
      dst[tx * 4 + j] = active ? (acc[i][j] + b_fc[n]) : 0.f;
    }
  }
}

// ---------------------------------------------------------------------------
extern "C" void kernel_launch(void* const* d_in, const int* in_sizes, int n_in,
                              void* d_out, int out_size, void* d_ws,
                              size_t ws_size, hipStream_t stream) {
  const float* encoder_out = (const float*)d_in[0];
  const int* encoded_captions = (const int*)d_in[1];
  const int* cap_len = (const int*)d_in[2];
  const float* W_enc = (const float*)d_in[3];
  const float* b_enc = (const float*)d_in[4];
  const float* W_dec = (const float*)d_in[5];
  const float* b_dec = (const float*)d_in[6];
  const float* w_full = (const float*)d_in[7];
  const float* b_full = (const float*)d_in[8];
  const float* emb_table = (const float*)d_in[9];
  const float* W_ih = (const float*)d_in[10];
  const float* W_hh = (const float*)d_in[11];
  const float* b_ih = (const float*)d_in[12];
  const float* b_hh = (const float*)d_in[13];
  const float* W_init_h = (const float*)d_in[14];
  const float* b_init_h = (const float*)d_in[15];
  const float* W_init_c = (const float*)d_in[16];
  const float* b_init_c = (const float*)d_in[17];
  const float* W_f_beta = (const float*)d_in[18];
  const float* b_f_beta = (const float*)d_in[19];
  const float* W_fc = (const float*)d_in[20];
  const float* b_fc = (const float*)d_in[21];

  float* out = (float*)d_out;
  float* out_pred = out;
  float* out_caps = out_pred + (size_t)BB * TSTEPS * VDIM;
  float* out_declen = out_caps + BB * MAXLEN;
  float* out_alphas = out_declen + BB;
  float* out_order = out_alphas + (size_t)BB * TSTEPS * PP;

  float* w = (float*)d_ws;
  float* WfcT = w + WS_WFCT;
  float* ea = w + WS_EA;
  float* WcatT = w + WS_WCATT;
  float* WencT = w + WS_WENCT;
  float* WdecT = w + WS_WDECT;
  float* WfbT = w + WS_WFBT;
  float* WihT_ = w + WS_WIHT;
  float* WicT_ = w + WS_WICT;
  float* mean_enc = w + WS_MEAN;
  float* h = w + WS_H;
  float* c = w + WS_C;
  float* ctx = w + WS_CTX;
  float* gate = w + WS_GATE;
  float* g = w + WS_G;
  int* order_i = (int*)(w + WS_ORDER);
  int* declen_i = (int*)(w + WS_DECLEN);

  dim3 tb(32, 8);
  // Sort + int outputs
  k_sort<<<1, 64, 0, stream>>>(cap_len, encoded_captions, out_caps, out_declen,
                               out_order, order_i, declen_i);
  // Transposes (run every call: ws is re-poisoned between launches)
  k_transpose<<<dim3(16, 16), tb, 0, stream>>>(W_enc, 512, 512, WencT, 512);
  k_transpose<<<dim3(16, 16), tb, 0, stream>>>(W_dec, 512, 512, WdecT, 512);
  k_transpose<<<dim3(16, 16), tb, 0, stream>>>(W_f_beta, 512, 512, WfbT, 512);
  k_transpose<<<dim3(16, 16), tb, 0, stream>>>(W_init_h, 512, 512, WihT_, 512);
  k_transpose<<<dim3(16, 16), tb, 0, stream>>>(W_init_c, 512, 512, WicT_, 512);
  k_transpose<<<dim3(32, 64), tb, 0, stream>>>(W_ih, 2048, 1024, WcatT, GDIM);
  k_transpose<<<dim3(16, 64), tb, 0, stream>>>(W_hh, 2048, 512,
                                               WcatT + 1024ull * GDIM, GDIM);
  k_transpose<<<dim3(16, 1000), tb, 0, stream>>>(W_fc, VDIM, 512, WfcT, VDIM);
  // Prologue compute
  k_mean<<<64, 256, 0, stream>>>(encoder_out, order_i, mean_enc);
  k_init_hc<<<64, 256, 0, stream>>>(mean_enc, WihT_, b_init_h, WicT_, b_init_c,
                                    h, c);
  k_ea_gemm<<<dim3(196, 8), 256, 0, stream>>>(encoder_out, order_i, WencT,
                                              b_enc, ea);
  // Decode loop: 50 sequential steps
  for (int t = 0; t < TSTEPS; ++t) {
    k_att<<<128, 256, 0, stream>>>(h, WdecT, b_dec, ea, w_full, b_full,
                                   encoder_out, order_i, declen_i, WfbT,
                                   b_f_beta, ctx, gate, out_alphas, t);
    k_gates<<<32, 256, 0, stream>>>(emb_table, encoded_captions, order_i, ctx,
                                    gate, h, WcatT, g, t);
    k_lstm_pw<<<64, 512, 0, stream>>>(g, b_ih, b_hh, h, c);
    k_fc<<<500, 256, 0, stream>>>(h, WfcT, b_fc, declen_i, out_pred, t);
  }
}

// Round 2
// 6711.969 us; speedup vs baseline: 1.8662x; 1.8662x over previous
//
#include <hip/hip_runtime.h>
#include <hip/hip_bf16.h>
#include <math.h>

// Problem constants
#define BB      64
#define PP      196      // 14*14
#define ENCD    512
#define ADIM    512
#define DDIM    512
#define EDIM    512
#define VDIM    32000
#define MAXLEN  51
#define TSTEPS  50       // MAXLEN - 1
#define KCAT    1536     // E + ENC + D
#define GDIM    2048     // 4*D

typedef __attribute__((ext_vector_type(8))) short bf16x8;
typedef __attribute__((ext_vector_type(4))) float f32x4;

__device__ __forceinline__ ushort f2b(float x) {
  __hip_bfloat16 h = __float2bfloat16(x);
  return *reinterpret_cast<ushort*>(&h);
}
__device__ __forceinline__ float b2f(ushort u) {
  unsigned v = ((unsigned)u) << 16;
  return __uint_as_float(v);
}

// ---------------------------------------------------------------------------
// Workspace layout (byte offsets), total ~70 MB (prev round used ~110 MB OK).
#define OFF_WFCB   0ull            // 32,768,000  bf16 W_fc (32000x512 row-major)
#define OFF_WCATB  32768000ull     //  6,291,456  bf16 [W_ih|W_hh] rows (2048x1536)
#define OFF_WDGB   39059456ull     //  1,048,576  bf16 [W_dec;W_f_beta] rows (1024x512)
#define OFF_WENCB  40108032ull     //    524,288  bf16 W_enc (512x512)
#define OFF_ENCB   40632320ull     // 12,845,056  bf16 enc sorted (64x196x512)
#define OFF_EAB    53477376ull     // 12,845,056  bf16 ea (64x196x512)
#define OFF_WIHT   66322432ull     //  1,048,576  f32 W_init_h^T
#define OFF_WICT   67371008ull     //  1,048,576  f32 W_init_c^T
#define OFF_MEAN   68419584ull     //    131,072  f32 mean_enc
#define OFF_C      68550656ull     //    131,072  f32 cell state
#define OFF_HB     68681728ull     //     65,536  bf16 h state (64x512)
#define OFF_DA     68747264ull     //    131,072  f32 da (64x512)
#define OFF_GATE   68878336ull     //    131,072  f32 gate (64x512)
#define OFF_XCATB  69009408ull     //    196,608  bf16 [emb|gate*ctx|h] (64x1536)
#define OFF_G      69206016ull     //    524,288  f32 gates preact (64x2048)
#define OFF_ORDER  69730304ull
#define OFF_DECLEN 69730560ull

// ---------------------------------------------------------------------------
__global__ __launch_bounds__(64) void k_sort(
    const int* __restrict__ cap_len, const int* __restrict__ caps,
    float* __restrict__ out_caps, float* __restrict__ out_declen,
    float* __restrict__ out_order, int* __restrict__ order_i,
    int* __restrict__ declen_i) {
  __shared__ int lens[BB];
  __shared__ int ord[BB];
  int i = threadIdx.x;
  lens[i] = cap_len[i];
  __syncthreads();
  int li = lens[i];
  int rank = 0;
  for (int j = 0; j < BB; ++j) {
    int lj = lens[j];
    if (lj > li || (lj == li && j < i)) rank++;
  }
  ord[rank] = i;
  __syncthreads();
  int ob = ord[i];
  order_i[i] = ob;
  int dl = lens[ob] - 1;
  declen_i[i] = dl;
  out_declen[i] = (float)dl;
  out_order[i] = (float)ob;
  for (int j = 0; j < MAXLEN; ++j)
    out_caps[i * MAXLEN + j] = (float)caps[ob * MAXLEN + j];
}

// ---------------------------------------------------------------------------
// fp32 -> bf16 convert, vectorized x4. n multiple of 1024*gridDim handled by
// grid-stride.
__global__ __launch_bounds__(256) void k_cvt(
    const float* __restrict__ src, ushort* __restrict__ dst, int n4) {
  for (int i = blockIdx.x * 256 + threadIdx.x; i < n4; i += gridDim.x * 256) {
    float4 v = *(const float4*)(src + 4 * (size_t)i);
    ushort4 o;
    o.x = f2b(v.x); o.y = f2b(v.y); o.z = f2b(v.z); o.w = f2b(v.w);
    *(ushort4*)(dst + 4 * (size_t)i) = o;
  }
}

// Wcatb row n (2048 rows): [W_ih row n (1024) | W_hh row n (512)] as bf16.
__global__ __launch_bounds__(384) void k_cvt_cat(
    const float* __restrict__ W_ih, const float* __restrict__ W_hh,
    ushort* __restrict__ dst) {
  int n = blockIdx.x;
  int k = threadIdx.x * 4;
  const float* src = (k < 1024) ? (W_ih + (size_t)n * 1024 + k)
                                : (W_hh + (size_t)n * 512 + (k - 1024));
  float4 v = *(const float4*)src;
  ushort4 o;
  o.x = f2b(v.x); o.y = f2b(v.y); o.z = f2b(v.z); o.w = f2b(v.w);
  *(ushort4*)(dst + (size_t)n * KCAT + k) = o;
}

// Wdgb row n (1024 rows): n<512 -> W_dec row n; else W_f_beta row n-512.
__global__ __launch_bounds__(128) void k_cvt_dg(
    const float* __restrict__ W_dec, const float* __restrict__ W_fb,
    ushort* __restrict__ dst) {
  int n = blockIdx.x;
  int k = threadIdx.x * 4;
  const float* src = (n < 512) ? (W_dec + (size_t)n * 512 + k)
                               : (W_fb + (size_t)(n - 512) * 512 + k);
  float4 v = *(const float4*)src;
  ushort4 o;
  o.x = f2b(v.x); o.y = f2b(v.y); o.z = f2b(v.z); o.w = f2b(v.w);
  *(ushort4*)(dst + (size_t)n * 512 + k) = o;
}

// encb = bf16(enc[order]) ; grid (98, 64): 1024 elems per block.
__global__ __launch_bounds__(256) void k_encb(
    const float* __restrict__ enc, const int* __restrict__ order_i,
    ushort* __restrict__ encb) {
  int b = blockIdx.y;
  int ob = order_i[b];
  int off = blockIdx.x * 1024 + threadIdx.x * 4;
  float4 v = *(const float4*)(enc + (size_t)ob * (PP * ENCD) + off);
  ushort4 o;
  o.x = f2b(v.x); o.y = f2b(v.y); o.z = f2b(v.z); o.w = f2b(v.w);
  *(ushort4*)(encb + (size_t)b * (PP * ENCD) + off) = o;
}

// ---------------------------------------------------------------------------
__global__ __launch_bounds__(256) void k_transpose(
    const float* __restrict__ src, int R, int C,
    float* __restrict__ dst, int dstLD) {
  __shared__ float tile[32][33];
  int tx = threadIdx.x, ty = threadIdx.y;   // 32 x 8
  int c0 = blockIdx.x * 32, r0 = blockIdx.y * 32;
  for (int i = ty; i < 32; i += 8)
    tile[i][tx] = src[(size_t)(r0 + i) * C + (c0 + tx)];
  __syncthreads();
  for (int i = ty; i < 32; i += 8)
    dst[(size_t)(c0 + i) * dstLD + (r0 + tx)] = tile[tx][i];
}

// ---------------------------------------------------------------------------
__global__ __launch_bounds__(256) void k_mean(
    const float* __restrict__ enc, const int* __restrict__ order_i,
    float* __restrict__ mean_enc) {
  int b = blockIdx.x;
  int ob = order_i[b];
  const float* src = enc + (size_t)ob * PP * ENCD;
  for (int e = threadIdx.x; e < ENCD; e += 256) {
    float acc = 0.f;
    for (int p = 0; p < PP; ++p) acc += src[p * ENCD + e];
    mean_enc[b * ENCD + e] = acc * (1.f / PP);
  }
}

// ---------------------------------------------------------------------------
__global__ __launch_bounds__(256) void k_init_hc(
    const float* __restrict__ mean_enc, const float* __restrict__ WhT,
    const float* __restrict__ bh, const float* __restrict__ WcT,
    const float* __restrict__ bc, ushort* __restrict__ hb,
    float* __restrict__ c) {
  __shared__ float m[ENCD];
  int b = blockIdx.x;
  for (int k = threadIdx.x; k < ENCD; k += 256) m[k] = mean_enc[b * ENCD + k];
  __syncthreads();
  for (int d = threadIdx.x; d < DDIM; d += 256) {
    float ah = bh[d], ac = bc[d];
    for (int k = 0; k < ENCD; ++k) {
      float mv = m[k];
      ah += mv * WhT[k * DDIM + d];
      ac += mv * WcT[k * DDIM + d];
    }
    hb[b * DDIM + d] = f2b(ah);
    c[b * DDIM + d] = ac;
  }
}

// ---------------------------------------------------------------------------
// MFMA GEMM: ea = encb @ W_enc^T + b_enc -> bf16 eab. M=12544, N=512, K=512.
// grid (4, 196); block tile 64(M) x 128(N); wave handles 64x32.
__global__ __launch_bounds__(256) void k_ea_mfma(
    const ushort* __restrict__ encb, const ushort* __restrict__ Wencb,
    const float* __restrict__ b_enc, ushort* __restrict__ eab) {
  int tid = threadIdx.x, wave = tid >> 6, lane = tid & 63;
  int quad = lane >> 4, lr = lane & 15;
  int m0 = blockIdx.y * 64;
  int n0 = blockIdx.x * 128 + wave * 32;
  const ushort* Arow = encb + ((size_t)(m0 + lr)) * 512 + quad * 8;
  const ushort* B0 = Wencb + (size_t)(n0 + lr) * 512 + quad * 8;
  const ushort* B1 = B0 + 16 * 512;
  f32x4 acc[4][2] = {};
  for (int k0 = 0; k0 < 512; k0 += 32) {
    bf16x8 b0 = *reinterpret_cast<const bf16x8*>(B0 + k0);
    bf16x8 b1 = *reinterpret_cast<const bf16x8*>(B1 + k0);
#pragma unroll
    for (int mt = 0; mt < 4; ++mt) {
      bf16x8 a = *reinterpret_cast<const bf16x8*>(Arow + mt * 16 * 512 + k0);
      acc[mt][0] = __builtin_amdgcn_mfma_f32_16x16x32_bf16(a, b0, acc[mt][0], 0, 0, 0);
      acc[mt][1] = __builtin_amdgcn_mfma_f32_16x16x32_bf16(a, b1, acc[mt][1], 0, 0, 0);
    }
  }
#pragma unroll
  for (int mt = 0; mt < 4; ++mt)
#pragma unroll
    for (int nt = 0; nt < 2; ++nt) {
      int col = n0 + nt * 16 + lr;
      float bias = b_enc[col];
#pragma unroll
      for (int r = 0; r < 4; ++r) {
        int row = m0 + mt * 16 + quad * 4 + r;
        eab[(size_t)row * 512 + col] = f2b(acc[mt][nt][r] + bias);
      }
    }
}

// ---------------------------------------------------------------------------
// MFMA GEMM: [da | gate] = h @ [W_dec;W_f_beta]^T. M=64, N=1024, K=512.
// grid 8 blocks x 128 cols.
__global__ __launch_bounds__(256) void k_dagate(
    const ushort* __restrict__ hb, const ushort* __restrict__ Wdgb,
    const float* __restrict__ b_dec, const float* __restrict__ b_fb,
    float* __restrict__ da, float* __restrict__ gate) {
  int tid = threadIdx.x, wave = tid >> 6, lane = tid & 63;
  int quad = lane >> 4, lr = lane & 15;
  int n0 = blockIdx.x * 128 + wave * 32;
  const ushort* Arow = hb + (size_t)lr * 512 + quad * 8;
  const ushort* B0 = Wdgb + (size_t)(n0 + lr) * 512 + quad * 8;
  const ushort* B1 = B0 + 16 * 512;
  f32x4 acc[4][2] = {};
  for (int k0 = 0; k0 < 512; k0 += 32) {
    bf16x8 b0 = *reinterpret_cast<const bf16x8*>(B0 + k0);
    bf16x8 b1 = *reinterpret_cast<const bf16x8*>(B1 + k0);
#pragma unroll
    for (int mt = 0; mt < 4; ++mt) {
      bf16x8 a = *reinterpret_cast<const bf16x8*>(Arow + mt * 16 * 512 + k0);
      acc[mt][0] = __builtin_amdgcn_mfma_f32_16x16x32_bf16(a, b0, acc[mt][0], 0, 0, 0);
      acc[mt][1] = __builtin_amdgcn_mfma_f32_16x16x32_bf16(a, b1, acc[mt][1], 0, 0, 0);
    }
  }
#pragma unroll
  for (int mt = 0; mt < 4; ++mt)
#pragma unroll
    for (int nt = 0; nt < 2; ++nt) {
      int col = n0 + nt * 16 + lr;
#pragma unroll
      for (int r = 0; r < 4; ++r) {
        int row = mt * 16 + quad * 4 + r;
        float v = acc[mt][nt][r];
        if (col < 512) {
          da[row * 512 + col] = v + b_dec[col];
        } else {
          int cg = col - 512;
          gate[row * 512 + cg] = 1.f / (1.f + expf(-(v + b_fb[cg])));
        }
      }
    }
}

// ---------------------------------------------------------------------------
// Attention per batch element (64 blocks): scores -> softmax -> alphas + ctx,
// plus builds xcatb row = [bf16(emb[tok]) | bf16(gate*ctx) | hb].
__global__ __launch_bounds__(256) void k_att2(
    const float* __restrict__ da, const ushort* __restrict__ eab,
    const float* __restrict__ w_full, const ushort* __restrict__ encb,
    const float* __restrict__ gate, const float* __restrict__ emb_table,
    const int* __restrict__ caps, const int* __restrict__ order_i,
    const int* __restrict__ declen_i, const ushort* __restrict__ hb,
    ushort* __restrict__ xcatb, float* __restrict__ out_alphas, int t) {
  __shared__ float das[ADIM];
  __shared__ float wf[ADIM];
  __shared__ float sc[PP];
  int b = blockIdx.x;
  int tid = threadIdx.x;
  int wave = tid >> 6, lane = tid & 63;
  for (int i = tid; i < ADIM; i += 256) {
    das[i] = da[b * ADIM + i];
    wf[i] = w_full[i];
  }
  // emb + h parts of xcat (independent of softmax)
  int tok = caps[order_i[b] * MAXLEN + t];
  for (int j = tid; j < 512; j += 256) {
    xcatb[(size_t)b * KCAT + j] = f2b(emb_table[(size_t)tok * EDIM + j]);
    xcatb[(size_t)b * KCAT + 1024 + j] = hb[b * 512 + j];
  }
  __syncthreads();
  // scores: each lane handles 8 consecutive a-elements
  for (int p = wave; p < PP; p += 4) {
    const ushort* ep = eab + ((size_t)b * PP + p) * ADIM + lane * 8;
    bf16x8 ev = *reinterpret_cast<const bf16x8*>(ep);
    float s = 0.f;
#pragma unroll
    for (int j = 0; j < 8; ++j) {
      int a = lane * 8 + j;
      float e = b2f((ushort)ev[j]);
      s += fmaxf(e + das[a], 0.f) * wf[a];
    }
#pragma unroll
    for (int off = 32; off; off >>= 1) s += __shfl_xor(s, off);
    if (lane == 0) sc[p] = s;
  }
  __syncthreads();
  if (wave == 0) {  // softmax over 196
    float m = -1e30f;
    for (int p = lane; p < PP; p += 64) m = fmaxf(m, sc[p]);
#pragma unroll
    for (int off = 32; off; off >>= 1) m = fmaxf(m, __shfl_xor(m, off));
    float ssum = 0.f;
    for (int p = lane; p < PP; p += 64) {
      float e = expf(sc[p] - m);
      sc[p] = e;
      ssum += e;
    }
#pragma unroll
    for (int off = 32; off; off >>= 1) ssum += __shfl_xor(ssum, off);
    float inv = 1.f / ssum;
    for (int p = lane; p < PP; p += 64) sc[p] *= inv;
  }
  __syncthreads();
  int active = t < declen_i[b];
  for (int p = tid; p < PP; p += 256)
    out_alphas[((size_t)b * TSTEPS + t) * PP + p] = active ? sc[p] : 0.f;
  // ctx (pairs): thread handles e0=2*tid, e0+1; writes gate*ctx as bf16
  int e0 = tid * 2;
  float cx = 0.f, cy = 0.f;
  const ushort* eb = encb + (size_t)b * (PP * ENCD) + e0;
  for (int p = 0; p < PP; ++p) {
    float a = sc[p];
    ushort2 uv = *(const ushort2*)(eb + (size_t)p * ENCD);
    cx += a * b2f(uv.x);
    cy += a * b2f(uv.y);
  }
  cx *= gate[b * ENCD + e0];
  cy *= gate[b * ENCD + e0 + 1];
  xcatb[(size_t)b * KCAT + 512 + e0] = f2b(cx);
  xcatb[(size_t)b * KCAT + 512 + e0 + 1] = f2b(cy);
}

// ---------------------------------------------------------------------------
// MFMA GEMM: g = xcat @ [W_ih|W_hh]^T. M=64, N=2048, K=1536. grid 16 blocks.
__global__ __launch_bounds__(256) void k_gates_mfma(
    const ushort* __restrict__ xcatb, const ushort* __restrict__ Wcatb,
    float* __restrict__ g) {
  int tid = threadIdx.x, wave = tid >> 6, lane = tid & 63;
  int quad = lane >> 4, lr = lane & 15;
  int n0 = blockIdx.x * 128 + wave * 32;
  const ushort* Arow = xcatb + (size_t)lr * KCAT + quad * 8;
  const ushort* B0 = Wcatb + (size_t)(n0 + lr) * KCAT + quad * 8;
  const ushort* B1 = B0 + 16 * KCAT;
  f32x4 acc[4][2] = {};
  for (int k0 = 0; k0 < KCAT; k0 += 32) {
    bf16x8 b0 = *reinterpret_cast<const bf16x8*>(B0 + k0);
    bf16x8 b1 = *reinterpret_cast<const bf16x8*>(B1 + k0);
#pragma unroll
    for (int mt = 0; mt < 4; ++mt) {
      bf16x8 a = *reinterpret_cast<const bf16x8*>(Arow + mt * 16 * KCAT + k0);
      acc[mt][0] = __builtin_amdgcn_mfma_f32_16x16x32_bf16(a, b0, acc[mt][0], 0, 0, 0);
      acc[mt][1] = __builtin_amdgcn_mfma_f32_16x16x32_bf16(a, b1, acc[mt][1], 0, 0, 0);
    }
  }
#pragma unroll
  for (int mt = 0; mt < 4; ++mt)
#pragma unroll
    for (int nt = 0; nt < 2; ++nt) {
      int col = n0 + nt * 16 + lr;
#pragma unroll
      for (int r = 0; r < 4; ++r) {
        int row = mt * 16 + quad * 4 + r;
        g[(size_t)row * GDIM + col] = acc[mt][nt][r];
      }
    }
}

// ---------------------------------------------------------------------------
__global__ __launch_bounds__(512) void k_lstm_pw(
    const float* __restrict__ g, const float* __restrict__ b_ih,
    const float* __restrict__ b_hh, ushort* __restrict__ hb,
    float* __restrict__ c) {
  int b = blockIdx.x, d = threadIdx.x;
  float gi = g[b * GDIM + d] + b_ih[d] + b_hh[d];
  float gf = g[b * GDIM + 512 + d] + b_ih[512 + d] + b_hh[512 + d];
  float gg = g[b * GDIM + 1024 + d] + b_ih[1024 + d] + b_hh[1024 + d];
  float go = g[b * GDIM + 1536 + d] + b_ih[1536 + d] + b_hh[1536 + d];
  float si = 1.f / (1.f + expf(-gi));
  float sf = 1.f / (1.f + expf(-gf));
  float so = 1.f / (1.f + expf(-go));
  float cn = sf * c[b * DDIM + d] + si * tanhf(gg);
  float hn = so * tanhf(cn);
  c[b * DDIM + d] = cn;
  hb[b * DDIM + d] = f2b(hn);
}

// ---------------------------------------------------------------------------
// MFMA GEMM: preds = h @ W_fc^T + b_fc (masked). M=64, N=32000, K=512.
// grid 250 blocks x 128 cols.
__global__ __launch_bounds__(256) void k_fc_mfma(
    const ushort* __restrict__ hb, const ushort* __restrict__ Wfcb,
    const float* __restrict__ b_fc, const int* __restrict__ declen_i,
    float* __restrict__ out_pred, int t) {
  __shared__ int dls[64];
  int tid = threadIdx.x, wave = tid >> 6, lane = tid & 63;
  int quad = lane >> 4, lr = lane & 15;
  if (tid < 64) dls[tid] = declen_i[tid];
  int n0 = blockIdx.x * 128 + wave * 32;
  const ushort* Arow = hb + (size_t)lr * 512 + quad * 8;
  const ushort* B0 = Wfcb + (size_t)(n0 + lr) * 512 + quad * 8;
  const ushort* B1 = B0 + 16 * 512;
  f32x4 acc[4][2] = {};
  for (int k0 = 0; k0 < 512; k0 += 32) {
    bf16x8 b0 = *reinterpret_cast<const bf16x8*>(B0 + k0);
    bf16x8 b1 = *reinterpret_cast<const bf16x8*>(B1 + k0);
#pragma unroll
    for (int mt = 0; mt < 4; ++mt) {
      bf16x8 a = *reinterpret_cast<const bf16x8*>(Arow + mt * 16 * 512 + k0);
      acc[mt][0] = __builtin_amdgcn_mfma_f32_16x16x32_bf16(a, b0, acc[mt][0], 0, 0, 0);
      acc[mt][1] = __builtin_amdgcn_mfma_f32_16x16x32_bf16(a, b1, acc[mt][1], 0, 0, 0);
    }
  }
  __syncthreads();
#pragma unroll
  for (int mt = 0; mt < 4; ++mt)
#pragma unroll
    for (int nt = 0; nt < 2; ++nt) {
      int col = n0 + nt * 16 + lr;
      float bias = b_fc[col];
#pragma unroll
      for (int r = 0; r < 4; ++r) {
        int row = mt * 16 + quad * 4 + r;
        int active = t < dls[row];
        out_pred[((size_t)row * TSTEPS + t) * VDIM + col] =
            active ? (acc[mt][nt][r] + bias) : 0.f;
      }
    }
}

// ---------------------------------------------------------------------------
extern "C" void kernel_launch(void* const* d_in, const int* in_sizes, int n_in,
                              void* d_out, int out_size, void* d_ws,
                              size_t ws_size, hipStream_t stream) {
  const float* encoder_out = (const float*)d_in[0];
  const int* encoded_captions = (const int*)d_in[1];
  const int* cap_len = (const int*)d_in[2];
  const float* W_enc = (const float*)d_in[3];
  const float* b_enc = (const float*)d_in[4];
  const float* W_dec = (const float*)d_in[5];
  const float* b_dec = (const float*)d_in[6];
  const float* w_full = (const float*)d_in[7];
  // d_in[8] = b_full (scalar; softmax-invariant, omitted)
  const float* emb_table = (const float*)d_in[9];
  const float* W_ih = (const float*)d_in[10];
  const float* W_hh = (const float*)d_in[11];
  const float* b_ih = (const float*)d_in[12];
  const float* b_hh = (const float*)d_in[13];
  const float* W_init_h = (const float*)d_in[14];
  const float* b_init_h = (const float*)d_in[15];
  const float* W_init_c = (const float*)d_in[16];
  const float* b_init_c = (const float*)d_in[17];
  const float* W_f_beta = (const float*)d_in[18];
  const float* b_f_beta = (const float*)d_in[19];
  const float* W_fc = (const float*)d_in[20];
  const float* b_fc = (const float*)d_in[21];

  float* out = (float*)d_out;
  float* out_pred = out;
  float* out_caps = out_pred + (size_t)BB * TSTEPS * VDIM;
  float* out_declen = out_caps + BB * MAXLEN;
  float* out_alphas = out_declen + BB;
  float* out_order = out_alphas + (size_t)BB * TSTEPS * PP;

  char* base = (char*)d_ws;
  ushort* Wfcb = (ushort*)(base + OFF_WFCB);
  ushort* Wcatb = (ushort*)(base + OFF_WCATB);
  ushort* Wdgb = (ushort*)(base + OFF_WDGB);
  ushort* Wencb = (ushort*)(base + OFF_WENCB);
  ushort* encb = (ushort*)(base + OFF_ENCB);
  ushort* eab = (ushort*)(base + OFF_EAB);
  float* WihT = (float*)(base + OFF_WIHT);
  float* WicT = (float*)(base + OFF_WICT);
  float* meanb = (float*)(base + OFF_MEAN);
  float* c = (float*)(base + OFF_C);
  ushort* hb = (ushort*)(base + OFF_HB);
  float* da = (float*)(base + OFF_DA);
  float* gate = (float*)(base + OFF_GATE);
  ushort* xcatb = (ushort*)(base + OFF_XCATB);
  float* g = (float*)(base + OFF_G);
  int* order_i = (int*)(base + OFF_ORDER);
  int* declen_i = (int*)(base + OFF_DECLEN);

  dim3 tb(32, 8);
  k_sort<<<1, 64, 0, stream>>>(cap_len, encoded_captions, out_caps, out_declen,
                               out_order, order_i, declen_i);
  // weight conversions (one-time per call)
  k_cvt<<<2048, 256, 0, stream>>>(W_fc, Wfcb, 16384000 / 4);
  k_cvt<<<64, 256, 0, stream>>>(W_enc, Wencb, 262144 / 4);
  k_cvt_cat<<<2048, 384, 0, stream>>>(W_ih, W_hh, Wcatb);
  k_cvt_dg<<<1024, 128, 0, stream>>>(W_dec, W_f_beta, Wdgb);
  k_encb<<<dim3(98, 64), 256, 0, stream>>>(encoder_out, order_i, encb);
  k_transpose<<<dim3(16, 16), tb, 0, stream>>>(W_init_h, 512, 512, WihT, 512);
  k_transpose<<<dim3(16, 16), tb, 0, stream>>>(W_init_c, 512, 512, WicT, 512);
  // prologue compute
  k_mean<<<64, 256, 0, stream>>>(encoder_out, order_i, meanb);
  k_init_hc<<<64, 256, 0, stream>>>(meanb, WihT, b_init_h, WicT, b_init_c, hb, c);
  k_ea_mfma<<<dim3(4, 196), 256, 0, stream>>>(encb, Wencb, b_enc, eab);
  // decode loop
  for (int t = 0; t < TSTEPS; ++t) {
    k_dagate<<<8, 256, 0, stream>>>(hb, Wdgb, b_dec, b_f_beta, da, gate);
    k_att2<<<64, 256, 0, stream>>>(da, eab, w_full, encb, gate, emb_table,
                                   encoded_captions, order_i, declen_i, hb,
                                   xcatb, out_alphas, t);
    k_gates_mfma<<<16, 256, 0, stream>>>(xcatb, Wcatb, g);
    k_lstm_pw<<<64, 512, 0, stream>>>(g, b_ih, b_hh, hb, c);
    k_fc_mfma<<<250, 256, 0, stream>>>(hb, Wfcb, b_fc, declen_i, out_pred, t);
  }
}